// Round 1
// baseline (209.266 us; speedup 1.0000x reference)
//
#include <hip/hip_runtime.h>
#include <hip/hip_bf16.h>

// Problem constants (from reference): B=8, C=16, H=512, W=512, M=15, N=15
#define BC   128          // B*C
#define Hh   512
#define Ww   512
#define P16  16           // M+1
#define Q16  16           // N+1
#define HTILE 64          // h rows per block
#define NHT  (Hh / HTILE) // 8 h-tiles

// ---------------------------------------------------------------------------
// Kernel 1: extract separable factors from the provided basis input.
// basis[n, p, q] = Bu[h,p] * Bv[w,q] with n = h*W + w, and Bernstein rows sum
// to 1:  sum_q Bv[w,q] = 1, sum_p Bu[h,p] = 1 (to fp32 rounding).
// So: Bu[h,p] = sum_q basis[(h*W+0), p, q]   (w = 0 rows)
//     Bv[w,q] = sum_p basis[(0*W+w), p, q]   (h = 0 rows)
// ---------------------------------------------------------------------------
__global__ void extract_factors(const float* __restrict__ basis,
                                float* __restrict__ Bu,
                                float* __restrict__ Bv) {
    int t = blockIdx.x * blockDim.x + threadIdx.x;   // 0..1023
    if (t < Hh) {
        // Bu row h = t
        const float* row = basis + (size_t)t * Ww * (P16 * Q16);
        #pragma unroll
        for (int p = 0; p < P16; ++p) {
            float s = 0.f;
            #pragma unroll
            for (int q = 0; q < Q16; ++q) s += row[p * Q16 + q];
            Bu[t * P16 + p] = s;
        }
    } else if (t < Hh + Ww) {
        // Bv row w = t - 512
        int w = t - Hh;
        const float* row = basis + (size_t)w * (P16 * Q16);
        #pragma unroll
        for (int q = 0; q < Q16; ++q) {
            float s = 0.f;
            #pragma unroll
            for (int p = 0; p < P16; ++p) s += row[p * Q16 + q];
            Bv[w * Q16 + q] = s;
        }
    }
}

// ---------------------------------------------------------------------------
// Kernel 2: out[bc, h, w] = sum_p Bu[h,p] * ( sum_q K[bc,p,q] * Bv[w,q] )
// Block: one bc (blockIdx.y) x one 64-row h-tile (blockIdx.x), all 512 w.
// Phase A: build T[p][w] = sum_q K[p,q]*Bv[w,q] in LDS (16x512 floats).
// Phase B: each thread owns 4 consecutive w columns and 32 h rows.
// ---------------------------------------------------------------------------
__global__ __launch_bounds__(256, 4)
void bezier_eval(const float* __restrict__ K,
                 const float* __restrict__ Bu,
                 const float* __restrict__ Bv,
                 float* __restrict__ out) {
    __shared__ float Ts[P16][Ww];     // 32 KiB
    __shared__ float Bu_s[HTILE * P16]; // 4 KiB
    __shared__ float K_s[P16 * Q16];  // 1 KiB

    const int t     = threadIdx.x;       // 0..255
    const int htile = blockIdx.x;        // 0..7
    const int bc    = blockIdx.y;        // 0..127

    // --- loads: K panel (1 float/thread), Bu tile (float4/thread) ---
    K_s[t] = K[(size_t)bc * (P16 * Q16) + t];
    *(float4*)&Bu_s[t * 4] = *(const float4*)&Bu[htile * (HTILE * P16) + t * 4];
    __syncthreads();

    // --- Phase A: T[p][w] for w = 2t, 2t+1 ---
    {
        const int w0 = t * 2;
        const float* bvp = Bv + (size_t)w0 * Q16;   // two consecutive rows, 128 B
        float bv0[Q16], bv1[Q16];
        #pragma unroll
        for (int q = 0; q < Q16; ++q) { bv0[q] = bvp[q]; bv1[q] = bvp[Q16 + q]; }
        #pragma unroll
        for (int p = 0; p < P16; ++p) {
            float s0 = 0.f, s1 = 0.f;
            #pragma unroll
            for (int q = 0; q < Q16; ++q) {
                float k = K_s[p * Q16 + q];          // wave-uniform broadcast
                s0 = fmaf(k, bv0[q], s0);
                s1 = fmaf(k, bv1[q], s1);
            }
            *(float2*)&Ts[p][w0] = make_float2(s0, s1);  // ds_write_b64, contiguous
        }
    }
    __syncthreads();

    // --- Phase B: thread -> (w0 = (t&127)*4, h rows hhalf*32 .. +31) ---
    const int w0    = (t & 127) * 4;
    const int hhalf = t >> 7;            // 0 or 1

    float4 Tc[P16];                      // 64 VGPRs: T column slice
    #pragma unroll
    for (int p = 0; p < P16; ++p) Tc[p] = *(const float4*)&Ts[p][w0];

    const size_t out_row0 = ((size_t)bc * Hh + (size_t)htile * HTILE + hhalf * 32) * Ww + w0;

    #pragma unroll 4
    for (int h = 0; h < 32; ++h) {
        const int hh = hhalf * 32 + h;
        const float4* burow = (const float4*)&Bu_s[hh * P16];  // broadcast b128 reads
        float4 acc = make_float4(0.f, 0.f, 0.f, 0.f);
        #pragma unroll
        for (int p4 = 0; p4 < 4; ++p4) {
            float4 bu = burow[p4];
            #define FMA4(b, Tv) \
                acc.x = fmaf((b), (Tv).x, acc.x); \
                acc.y = fmaf((b), (Tv).y, acc.y); \
                acc.z = fmaf((b), (Tv).z, acc.z); \
                acc.w = fmaf((b), (Tv).w, acc.w);
            FMA4(bu.x, Tc[p4 * 4 + 0]);
            FMA4(bu.y, Tc[p4 * 4 + 1]);
            FMA4(bu.z, Tc[p4 * 4 + 2]);
            FMA4(bu.w, Tc[p4 * 4 + 3]);
            #undef FMA4
        }
        *(float4*)&out[out_row0 + (size_t)h * Ww] = acc;   // coalesced dwordx4
    }
}

extern "C" void kernel_launch(void* const* d_in, const int* in_sizes, int n_in,
                              void* d_out, int out_size, void* d_ws, size_t ws_size,
                              hipStream_t stream) {
    const float* K     = (const float*)d_in[0];   // [128, 16, 16]
    const float* basis = (const float*)d_in[1];   // [262144, 16, 16]
    float* out = (float*)d_out;                   // [128, 512, 512]

    float* Bu = (float*)d_ws;                     // [512][16]  (32 KiB)
    float* Bv = Bu + Hh * P16;                    // [512][16]  (32 KiB)

    extract_factors<<<4, 256, 0, stream>>>(basis, Bu, Bv);

    dim3 grid(NHT, BC);
    bezier_eval<<<grid, 256, 0, stream>>>(K, Bu, Bv, out);
}

// Round 3
// 44.633 us; speedup vs baseline: 4.6886x; 4.6886x over previous
//
#include <hip/hip_runtime.h>
#include <hip/hip_bf16.h>

// Problem constants (from reference): B=8, C=16, H=512, W=512, M=15, N=15
#define BC   128          // B*C
#define Hh   512
#define Ww   512
#define P16  16           // M+1
#define Q16  16           // N+1
#define HTILE 64          // h rows per block
#define NHT  (Hh / HTILE) // 8 h-tiles

typedef float f32x4 __attribute__((ext_vector_type(4)));  // native vec for nontemporal store

// ---------------------------------------------------------------------------
// Kernel 1: extract separable factors from the provided basis input.
// basis[n, p, q] = Bu[h,p] * Bv[w,q] with n = h*W + w, and Bernstein rows sum
// to 1:  sum_q Bv[w,q] = 1, sum_p Bu[h,p] = 1 (to fp32 rounding).
// So: Bu[h,p] = sum_q basis[(h*W+0), p, q]   (w = 0 rows)
//     Bv[w,q] = sum_p basis[(0*W+w), p, q]   (h = 0 rows)
// ---------------------------------------------------------------------------
__global__ void extract_factors(const float* __restrict__ basis,
                                float* __restrict__ Bu,
                                float* __restrict__ Bv) {
    int t = blockIdx.x * blockDim.x + threadIdx.x;   // 0..1023
    if (t < Hh) {
        const float* row = basis + (size_t)t * Ww * (P16 * Q16);
        #pragma unroll
        for (int p = 0; p < P16; ++p) {
            float s = 0.f;
            #pragma unroll
            for (int q = 0; q < Q16; ++q) s += row[p * Q16 + q];
            Bu[t * P16 + p] = s;
        }
    } else if (t < Hh + Ww) {
        int w = t - Hh;
        const float* row = basis + (size_t)w * (P16 * Q16);
        #pragma unroll
        for (int q = 0; q < Q16; ++q) {
            float s = 0.f;
            #pragma unroll
            for (int p = 0; p < P16; ++p) s += row[p * Q16 + q];
            Bv[w * Q16 + q] = s;
        }
    }
}

// ---------------------------------------------------------------------------
// Kernel 2: out[bc, h, w] = sum_p Bu[h,p] * ( sum_q K[bc,p,q] * Bv[w,q] )
// Block: one bc (blockIdx.y) x one 64-row h-tile (blockIdx.x), all 512 w.
// Phase A: build T[p][w] = sum_q K[p,q]*Bv[w,q] in LDS (16x512 floats).
// Phase B: T column slice held in 16 NAMED float4 registers (scratch-proof).
// ---------------------------------------------------------------------------
__global__ __launch_bounds__(256, 4)
void bezier_eval(const float* __restrict__ K,
                 const float* __restrict__ Bu,
                 const float* __restrict__ Bv,
                 float* __restrict__ out) {
    __shared__ float Ts[P16][Ww];        // 32 KiB
    __shared__ float Bu_s[HTILE * P16];  // 4 KiB
    __shared__ float K_s[P16 * Q16];     // 1 KiB

    const int t     = threadIdx.x;       // 0..255
    const int htile = blockIdx.x;        // 0..7
    const int bc    = blockIdx.y;        // 0..127

    // --- loads: K panel (1 float/thread), Bu tile (float4/thread) ---
    K_s[t] = K[(size_t)bc * (P16 * Q16) + t];
    *(float4*)&Bu_s[t * 4] = *(const float4*)&Bu[htile * (HTILE * P16) + t * 4];
    __syncthreads();

    // --- Phase A: T[p][w] for w = 2t, 2t+1 ---
    {
        const int w0 = t * 2;
        const float* bvp = Bv + (size_t)w0 * Q16;   // two consecutive rows, 128 B
        float bv0[Q16], bv1[Q16];
        #pragma unroll
        for (int q = 0; q < Q16; ++q) { bv0[q] = bvp[q]; bv1[q] = bvp[Q16 + q]; }
        #pragma unroll
        for (int p = 0; p < P16; ++p) {
            float s0 = 0.f, s1 = 0.f;
            #pragma unroll
            for (int q = 0; q < Q16; ++q) {
                float k = K_s[p * Q16 + q];          // wave-uniform broadcast
                s0 = fmaf(k, bv0[q], s0);
                s1 = fmaf(k, bv1[q], s1);
            }
            *(float2*)&Ts[p][w0] = make_float2(s0, s1);  // ds_write_b64, contiguous
        }
    }
    __syncthreads();

    // --- Phase B: thread -> (w0 = (t&127)*4, h rows hhalf*32 .. +31) ---
    const int w0    = (t & 127) * 4;
    const int hhalf = t >> 7;            // 0 or 1

    // 16 NAMED float4 registers — no array, no runtime indexing, no scratch.
    float4 T0  = *(const float4*)&Ts[ 0][w0];
    float4 T1  = *(const float4*)&Ts[ 1][w0];
    float4 T2  = *(const float4*)&Ts[ 2][w0];
    float4 T3  = *(const float4*)&Ts[ 3][w0];
    float4 T4  = *(const float4*)&Ts[ 4][w0];
    float4 T5  = *(const float4*)&Ts[ 5][w0];
    float4 T6  = *(const float4*)&Ts[ 6][w0];
    float4 T7  = *(const float4*)&Ts[ 7][w0];
    float4 T8  = *(const float4*)&Ts[ 8][w0];
    float4 T9  = *(const float4*)&Ts[ 9][w0];
    float4 T10 = *(const float4*)&Ts[10][w0];
    float4 T11 = *(const float4*)&Ts[11][w0];
    float4 T12 = *(const float4*)&Ts[12][w0];
    float4 T13 = *(const float4*)&Ts[13][w0];
    float4 T14 = *(const float4*)&Ts[14][w0];
    float4 T15 = *(const float4*)&Ts[15][w0];

    const size_t out_row0 = ((size_t)bc * Hh + (size_t)htile * HTILE + hhalf * 32) * Ww + w0;

    #pragma unroll 8
    for (int h = 0; h < 32; ++h) {
        const int hh = hhalf * 32 + h;
        const float4* burow = (const float4*)&Bu_s[hh * P16];  // broadcast b128 reads
        float4 b0 = burow[0], b1 = burow[1], b2 = burow[2], b3 = burow[3];
        float4 acc = make_float4(0.f, 0.f, 0.f, 0.f);
        #define FMA4(b, Tv) \
            acc.x = fmaf((b), (Tv).x, acc.x); \
            acc.y = fmaf((b), (Tv).y, acc.y); \
            acc.z = fmaf((b), (Tv).z, acc.z); \
            acc.w = fmaf((b), (Tv).w, acc.w);
        FMA4(b0.x, T0);  FMA4(b0.y, T1);  FMA4(b0.z, T2);  FMA4(b0.w, T3);
        FMA4(b1.x, T4);  FMA4(b1.y, T5);  FMA4(b1.z, T6);  FMA4(b1.w, T7);
        FMA4(b2.x, T8);  FMA4(b2.y, T9);  FMA4(b2.z, T10); FMA4(b2.w, T11);
        FMA4(b3.x, T12); FMA4(b3.y, T13); FMA4(b3.z, T14); FMA4(b3.w, T15);
        #undef FMA4
        // Streaming store via native vector type (builtin rejects HIP class float4).
        f32x4 accv = { acc.x, acc.y, acc.z, acc.w };
        __builtin_nontemporal_store(accv, (f32x4*)&out[out_row0 + (size_t)h * Ww]);
    }
}

extern "C" void kernel_launch(void* const* d_in, const int* in_sizes, int n_in,
                              void* d_out, int out_size, void* d_ws, size_t ws_size,
                              hipStream_t stream) {
    const float* K     = (const float*)d_in[0];   // [128, 16, 16]
    const float* basis = (const float*)d_in[1];   // [262144, 16, 16]
    float* out = (float*)d_out;                   // [128, 512, 512]

    float* Bu = (float*)d_ws;                     // [512][16]  (32 KiB)
    float* Bv = Bu + Hh * P16;                    // [512][16]  (32 KiB)

    extract_factors<<<4, 256, 0, stream>>>(basis, Bu, Bv);

    dim3 grid(NHT, BC);
    bezier_eval<<<grid, 256, 0, stream>>>(K, Bu, Bv, out);
}